// Round 11
// baseline (128.247 us; speedup 1.0000x reference)
//
#include <hip/hip_runtime.h>

// VQ: x (16,64,64,64) f32, codebook e (64,1024) f32. N=65536, D=64, K=1024.
//
// R17: R14/R15/R16 falsified occupancy, LDS-port, and instruction-stream
// theories (R16 halved ALL scoring instructions: zero change). The invariant
// across R6..R16 is the two UNTOUCHED scalar memory phases (A-build x-read,
// STE write): 4B/lane at 16KB stride, ~28MB HBM at an effective 420-530GB/s
// == the ~53us wall. R8's fallback proved 2+TB/s is achievable with wide
// deep requests => the phases are MLP/width-limited (guide G13: scalar f32
// ~2-2.5x slower). Fix: vectorize ONLY the memory phases:
//  - A-build: stage block's 32KB x-slice to LDS via float4-along-sp
//    (512B/wave-op), barrier, build bf16-split A-frags from LDS (bit-exact,
//    2-way-conflict-free reads).
//  - STE write: thread = 4 consecutive sp x 8 channels; float4 x re-read
//    (L2-hot), scalar e-gather (L2-resident), float4 store (1KB/wave-op).
//    Per-element fl(x + fl(q-x)) unchanged.
// Scoring (R16 32x32x16, 12 MFMA/tile), merge, certify, resolve: verbatim.

#define D 64
#define K 1024
#define NPOS 65536
#define HW 4096
#define XSTRIDE 262144  // D*HW
#define MARGIN 1.0e-3f

typedef float vfloat4  __attribute__((ext_vector_type(4)));
typedef float vfloat16 __attribute__((ext_vector_type(16)));
typedef short short8   __attribute__((ext_vector_type(8)));

static __device__ __forceinline__ unsigned short bf16_rne(float f) {
    unsigned u = __float_as_uint(f);
    u += 0x7FFFu + ((u >> 16) & 1u);
    return (unsigned short)(u >> 16);
}
static __device__ __forceinline__ float bf16_to_f32(unsigned short h) {
    return __uint_as_float(((unsigned)h) << 16);
}

// ---- prep: codebook -> bf16 split 32x32-B-fragments + c2n = -0.5*sum(e^2) -
// frag layout: ebf[tile][ks][split][lane][j], value = split(e[d][k]),
// d = ks*16 + (lane>>5)*8 + j, k = tile*32 + (lane&31). Tile = 8 KB.
__global__ void vq_prep(const float* __restrict__ e,
                        unsigned short* __restrict__ ebf,
                        float* __restrict__ c2n) {
    const int tile = blockIdx.x;               // 0..31
    const int t = threadIdx.x;
    const int l = t & 63;
    const int ks = t >> 6;                     // 0..3
    const int k = tile * 32 + (l & 31);
#pragma unroll
    for (int j = 0; j < 8; ++j) {
        const int d = ks * 16 + (l >> 5) * 8 + j;
        const float v = e[d * K + k];
        const unsigned short hh = bf16_rne(v);
        const float rem = v - bf16_to_f32(hh);     // exact (Sterbenz)
        const unsigned short hl = bf16_rne(rem);
        ebf[((size_t)(tile * 8 + ks * 2 + 0) * 64 + l) * 8 + j] = hh;
        ebf[((size_t)(tile * 8 + ks * 2 + 1) * 64 + l) * 8 + j] = hl;
    }
    if (t < 32) {
        const int kk = tile * 32 + t;
        float s = 0.f;
#pragma unroll
        for (int d = 0; d < D; ++d) {
            const float v = e[d * K + kk];     // sequential-d rounded squares
            s = s + __fmul_rn(v, v);
        }
        c2n[kk] = -0.5f * s;
    }
}

// ---- main: 512 blocks x 256 threads; block = 128 positions, 4 waves -------
__global__ __launch_bounds__(256, 2)
void vq_main(const float* __restrict__ x, const float* __restrict__ e,
             const unsigned short* __restrict__ ebf,
             const float* __restrict__ c2n,
             float* __restrict__ out) {
    __shared__ __align__(16) float xt[64][128];              // 32 KB x-tile
    __shared__ __align__(16) unsigned short lds_e[2][4096];  // 2 x 8 KB tiles
    __shared__ int   bk_lds[128];
    __shared__ int   lwl[128];
    __shared__ int   lwl_count;
    const int t = threadIdx.x;
    const int lane = t & 63;
    const int w = t >> 6;                      // wave 0..3 = position group
    const int p0 = blockIdx.x * 128;
    const int b = p0 >> 12;                    // 128 | 4096 -> single b
    const int sp0 = p0 & (HW - 1);
    const int c31 = lane & 31;                 // code column / A row
    const int hi = lane >> 5;                  // k-group half

    if (t == 0) lwl_count = 0;

    // ---- vectorized x-stage: float4 along sp, 512B/wave-op contiguous ----
    {
        const int spq = t & 31;                // sp quad 0..31
        const int d0 = t >> 5;                 // 0..7
        vfloat4 xs[8];
#pragma unroll
        for (int p = 0; p < 8; ++p) {          // d = p*8 + d0
            const int d = p * 8 + d0;
            xs[p] = *(const vfloat4*)(x + (size_t)b * XSTRIDE + (size_t)d * HW + sp0 + spq * 4);
        }
        // tile-0 ebf staging issued alongside (global -> reg)
        const short8 s0 = *(const short8*)(ebf + t * 8);
        const short8 s1v = *(const short8*)(ebf + 2048 + t * 8);
#pragma unroll
        for (int p = 0; p < 8; ++p)
            *(vfloat4*)(&xt[p * 8 + d0][spq * 4]) = xs[p];
        *(short8*)(&lds_e[0][t * 8]) = s0;
        *(short8*)(&lds_e[0][2048 + t * 8]) = s1v;
    }
    __syncthreads();                           // xt + tile0 in LDS

    // A-frags from LDS (bit-identical values): xh/xl for 4 K-steps (K=16)
    short8 ah[4], al[4];
    {
        const int pos = w * 32 + c31;          // this lane's position in tile
#pragma unroll
        for (int ks = 0; ks < 4; ++ks) {
            short8 fh, fl_;
#pragma unroll
            for (int j = 0; j < 8; ++j) {
                const int d = ks * 16 + hi * 8 + j;    // A[row=c31][k]
                const float v = xt[d][pos];
                const unsigned short h = bf16_rne(v);
                fh[j] = (short)h;
                fl_[j] = (short)bf16_rne(v - bf16_to_f32(h));
            }
            ah[ks] = fh; al[ks] = fl_;
        }
    }

    float s1[16], s2[16]; int t1[16];
#pragma unroll
    for (int r = 0; r < 16; ++r) { s1[r] = -3.4e38f; s2[r] = -3.4e38f; t1[r] = 0; }

    for (int tt = 0; tt < 32; ++tt) {
        const int cur = tt & 1;
        short8 stg0, stg1;
        if (tt < 31) {                         // issue early: hide L2 latency
            stg0 = *(const short8*)(ebf + (size_t)(tt + 1) * 4096 + t * 8);
            stg1 = *(const short8*)(ebf + (size_t)(tt + 1) * 4096 + 2048 + t * 8);
        }
        const short8* fb = (const short8*)(&lds_e[cur][0]);
        const float c2v = c2n[tt * 32 + c31];
        vfloat16 acc;
#pragma unroll
        for (int r = 0; r < 16; ++r) acc[r] = c2v;   // m = x.e - 0.5*c2
#pragma unroll
        for (int ks = 0; ks < 4; ++ks) {       // only 8 B-regs live at a time
            const short8 bh = fb[(ks * 2 + 0) * 64 + lane];
            const short8 bl = fb[(ks * 2 + 1) * 64 + lane];
            acc = __builtin_amdgcn_mfma_f32_32x32x16_bf16(ah[ks], bh, acc, 0, 0, 0);
            acc = __builtin_amdgcn_mfma_f32_32x32x16_bf16(al[ks], bh, acc, 0, 0, 0);
            acc = __builtin_amdgcn_mfma_f32_32x32x16_bf16(ah[ks], bl, acc, 0, 0, 0);
        }
#pragma unroll
        for (int r = 0; r < 16; ++r) {         // C/D: col=c31, row via r,hi
            const float m = acc[r];
            const bool gt = m > s1[r];
            s2[r] = __builtin_amdgcn_fmed3f(m, s1[r], s2[r]);  // second-best
            s1[r] = fmaxf(s1[r], m);
            t1[r] = gt ? tt : t1[r];
        }
        if (tt < 31) {                         // reg dep forces vmcnt wait
            *(short8*)(&lds_e[cur ^ 1][t * 8]) = stg0;
            *(short8*)(&lds_e[cur ^ 1][2048 + t * 8]) = stg1;
        }
        __syncthreads();                       // ds_write visible to all waves
    }

    // merge top-2 across the 32 code-columns (within each 32-lane half);
    // certify; push LOCAL worklist. Lanes 0 and 32 own 16 positions each.
#pragma unroll
    for (int r = 0; r < 16; ++r) {
        float a1 = s1[r], a2 = s2[r];
        int ak = t1[r] * 32 + c31;
#pragma unroll
        for (int m = 1; m < 32; m <<= 1) {     // masks <32 stay in-half
            const float o1 = __shfl_xor(a1, m, 64);
            const float o2 = __shfl_xor(a2, m, 64);
            const int   ok = __shfl_xor(ak, m, 64);
            const bool take = (o1 > a1) || (o1 == a1 && ok < ak);
            const float loser = take ? a1 : o1;
            a1 = take ? o1 : a1;
            ak = take ? ok : ak;
            a2 = fmaxf(fmaxf(a2, o2), loser);
        }
        if (c31 == 0) {
            const int pl = w * 32 + (r & 3) + 8 * (r >> 2) + hi * 4;
            bk_lds[pl] = ak;
            if (a1 - a2 <= 0.5f * MARGIN) {    // score gap = 2*(m1-m2)
                const int idx = atomicAdd(&lwl_count, 1);
                lwl[idx] = pl;
            }
        }
    }
    __syncthreads();

    // per-WAVE exact resolve (R9/R13-verified shfl-broadcast bit-exact scan)
    const int cnt = lwl_count;                 // uniform after barrier
    for (int i = w; i < cnt; i += 4) {
        const int pl = lwl[i];
        const int sp = sp0 + pl;
        // lane holds channel d=lane of this position; broadcast via shfl
        const float myx = x[(size_t)b * XSTRIDE + (size_t)lane * HW + sp];
        // Ap = np.sum(x**2) in numpy pairwise-8 order (verified grouping)
        float r8[8];
#pragma unroll
        for (int i0 = 0; i0 < 8; ++i0) {
            const float v = __shfl(myx, i0, 64);
            r8[i0] = __fmul_rn(v, v);
        }
#pragma unroll
        for (int j = 1; j < 8; ++j)
#pragma unroll
            for (int i0 = 0; i0 < 8; ++i0) {
                const float v = __shfl(myx, 8 * j + i0, 64);
                r8[i0] = r8[i0] + __fmul_rn(v, v);
            }
        const float Ap = ((r8[0] + r8[1]) + (r8[2] + r8[3])) + ((r8[4] + r8[5]) + (r8[6] + r8[7]));
        // 16 codes per lane (k = lane*16+m); sequential-d FMA chain per code
        float acc[16];
#pragma unroll
        for (int m = 0; m < 16; ++m) acc[m] = 0.f;
#pragma unroll 4
        for (int d = 0; d < D; ++d) {
            const float xd = __shfl(myx, d, 64);
            const vfloat4 e0 = *(const vfloat4*)(e + d * K + lane * 16);
            const vfloat4 e1 = *(const vfloat4*)(e + d * K + lane * 16 + 4);
            const vfloat4 e2 = *(const vfloat4*)(e + d * K + lane * 16 + 8);
            const vfloat4 e3 = *(const vfloat4*)(e + d * K + lane * 16 + 12);
#pragma unroll
            for (int c = 0; c < 4; ++c) {
                acc[c]      = __builtin_fmaf(xd, e0[c], acc[c]);
                acc[4 + c]  = __builtin_fmaf(xd, e1[c], acc[4 + c]);
                acc[8 + c]  = __builtin_fmaf(xd, e2[c], acc[8 + c]);
                acc[12 + c] = __builtin_fmaf(xd, e3[c], acc[12 + c]);
            }
        }
        float bs = 3.4e38f; int bk = 0x7fffffff;
#pragma unroll
        for (int m = 0; m < 16; ++m) {
            const int k = lane * 16 + m;       // ascending k per lane
            const float c2k = -2.0f * c2n[k];  // exact pow2 scale = np c2[k]
            const float sc = __builtin_fmaf(-2.f, acc[m], Ap) + c2k;
            if (sc < bs || (sc == bs && k < bk)) { bs = sc; bk = k; }
        }
#pragma unroll
        for (int mm = 1; mm < 64; mm <<= 1) {  // lane-major k order = global
            const float os = __shfl_xor(bs, mm, 64);
            const int   ok = __shfl_xor(bk, mm, 64);
            if (os < bs || (os == bs && ok < bk)) { bs = os; bk = ok; }
        }
        if (lane == 0) bk_lds[pl] = bk;        // exact index replaces approx
    }
    __syncthreads();

    // ---- vectorized STE write: thread = 4 consecutive sp x 8 channels ----
    // float4 x re-read (L2-hot), scalar e-gather (L2-resident), float4 store
    // (1 KB/wave-op). Per-element fl(x + fl(q-x)) unchanged => bit-exact.
    {
        const int spq = t & 31;                // sp quad
        const int cg = t >> 5;                 // channel group 0..7
        const int pl0 = spq * 4;
        const int bk0 = bk_lds[pl0 + 0];
        const int bk1 = bk_lds[pl0 + 1];
        const int bk2 = bk_lds[pl0 + 2];
        const int bk3 = bk_lds[pl0 + 3];
        const size_t base = (size_t)b * XSTRIDE + sp0 + pl0;
#pragma unroll
        for (int i = 0; i < 8; ++i) {
            const int c = cg * 8 + i;
            const vfloat4 xq = *(const vfloat4*)(x + base + (size_t)c * HW);
            vfloat4 qv;
            qv[0] = e[c * K + bk0];
            qv[1] = e[c * K + bk1];
            qv[2] = e[c * K + bk2];
            qv[3] = e[c * K + bk3];
            vfloat4 o;
#pragma unroll
            for (int j = 0; j < 4; ++j)
                o[j] = xq[j] + (qv[j] - xq[j]);   // np STE: fl(x + fl(q-x))
            *(vfloat4*)(out + base + (size_t)c * HW) = o;
        }
    }
}

extern "C" void kernel_launch(void* const* d_in, const int* in_sizes, int n_in,
                              void* d_out, int out_size, void* d_ws, size_t ws_size,
                              hipStream_t stream) {
    const float* x = (const float*)d_in[0];
    const float* e = (const float*)d_in[1];
    float* out = (float*)d_out;

    char* ws = (char*)d_ws;                          // ~260 KB used
    unsigned short* ebf = (unsigned short*)ws;       // 256 KB B-fragments
    float* c2n = (float*)(ws + 262144);              // 4 KB  (-0.5*sum e^2)

    vq_prep<<<32, 256, 0, stream>>>(e, ebf, c2n);
    vq_main<<<NPOS / 128, 256, 0, stream>>>(x, e, ebf, c2n, out);
}